// Round 10
// baseline (2333.467 us; speedup 1.0000x reference)
//
#include <hip/hip_runtime.h>

#define DT 5e-5f
#define SPRING_Y 30000.0f
#define DASHPOT 100.0f
// exp(-DT * DRAG_DAMPING) = exp(-5e-5)
#define DRAG 0.9999500012499792f

// xv layout: xv[2*i] = position, xv[2*i+1] = velocity (w unused).
// 32B per vertex, 32B-aligned -> both halves in ONE 64B line.
// adj entry: (neighbor, 1/rest as bits); force formula is symmetric, no sign.
// Stride layout: vertex v's entries at adj[v*64 .. v*64+deg[v]), slots filled
// by atomicAdd on deg during fill -- no count/scan kernels needed.
// STRIDE=64 >= max degree w.h.p. (Poisson(20) tail ~ e^-30).

// ---------- one-time (per launch) build ----------

__global__ void init_k(const float* __restrict__ x0, float4* __restrict__ xv,
                       int* __restrict__ deg, int nv) {
    int i = blockIdx.x * blockDim.x + threadIdx.x;
    if (i < nv) {
        xv[2 * i]     = make_float4(x0[3 * i], x0[3 * i + 1], x0[3 * i + 2], 0.0f);
        xv[2 * i + 1] = make_float4(0.0f, 0.0f, 0.0f, 0.0f);
        deg[i] = 0;
    }
}

__global__ void fill_stride_k(const int2* __restrict__ springs,
                              const float* __restrict__ rest,
                              int* __restrict__ deg, int2* __restrict__ adj,
                              int ns, int S) {
    int s = blockIdx.x * blockDim.x + threadIdx.x;
    if (s < ns) {
        int2 p = springs[s];
        int ir = __float_as_int(1.0f / rest[s]);
        int a = atomicAdd(&deg[p.x], 1);
        adj[p.x * S + a] = make_int2(p.y, ir);
        int b = atomicAdd(&deg[p.y], 1);
        adj[p.y * S + b] = make_int2(p.x, ir);
    }
}

// ---------- fused per-substep kernel: 4 lanes/vertex, 2 entries/lane/iter.
// Both gathers issue before any use (2 independent lines in flight per lane).
// Entry j always valid; entry j+4 clamped into this vertex's segment and
// arithmetically masked. adj reads use depth-1 prefetch (R6-proven). ----------

__device__ __forceinline__ void accum_pair(const float4& xa, const float4& va,
                                           const float4& xb, const float4& vb,
                                           float invr, float msk,
                                           float& fx, float& fy, float& fz) {
    float dx = xb.x - xa.x, dy = xb.y - xa.y, dz = xb.z - xa.z;
    float len = sqrtf(dx * dx + dy * dy + dz * dz);
    float il = 1.0f / len;                  // clamped dup entries are valid: len>0
    float ddx = dx * il, ddy = dy * il, ddz = dz * il;
    float vrel = (vb.x - va.x) * ddx + (vb.y - va.y) * ddy + (vb.z - va.z) * ddz;
    float coef = (SPRING_Y * (len * invr - 1.0f) + DASHPOT * vrel) * msk;
    fx += coef * ddx;
    fy += coef * ddy;
    fz += coef * ddz;
}

__global__ void __launch_bounds__(256) substep_k(
        const float4* __restrict__ xvin, float4* __restrict__ xvout,
        const int2* __restrict__ adj, const int* __restrict__ deg,
        const float* __restrict__ mass, int nv, int S) {
    int gid = blockIdx.x * blockDim.x + threadIdx.x;
    int vid = gid >> 2;
    int sub = gid & 3;
    if (vid >= nv) return;

    float4 xa = xvin[2 * vid];
    float4 va = xvin[2 * vid + 1];
    int s0 = vid * S;
    int s1 = s0 + deg[vid];
    int last = s1 - 1;                      // clamp stays inside this segment

    float fx = 0.0f, fy = 0.0f, fz = 0.0f;
    int j = s0 + sub;
    if (j < s1) {
        int2 e0 = adj[j];
        int2 e1 = adj[min(j + 4, last)];
        for (;;) {
            int jn = j + 8;
            // depth-1 adj prefetch for next iteration (clamped, in-segment)
            int2 e0n = adj[min(jn, last)];
            int2 e1n = adj[min(jn + 4, last)];

            // issue both xv gathers before any use
            float4 xb0 = xvin[2 * e0.x];
            float4 vb0 = xvin[2 * e0.x + 1];
            float4 xb1 = xvin[2 * e1.x];
            float4 vb1 = xvin[2 * e1.x + 1];

            float m1 = (j + 4 < s1) ? 1.0f : 0.0f;
            accum_pair(xa, va, xb0, vb0, __int_as_float(e0.y), 1.0f, fx, fy, fz);
            accum_pair(xa, va, xb1, vb1, __int_as_float(e1.y), m1, fx, fy, fz);

            if (jn >= s1) break;
            j = jn;
            e0 = e0n;
            e1 = e1n;
        }
    }

    // reduce across the 4 lanes of this vertex (xor stays within the group)
    fx += __shfl_xor(fx, 1);
    fx += __shfl_xor(fx, 2);
    fy += __shfl_xor(fy, 1);
    fy += __shfl_xor(fy, 2);
    fz += __shfl_xor(fz, 1);
    fz += __shfl_xor(fz, 2);

    if (sub == 0) {
        float m = mass[vid];
        fz += m * (-9.8f);
        float invm = 1.0f / m;

        va.x = (va.x + DT * fx * invm) * DRAG;
        va.y = (va.y + DT * fy * invm) * DRAG;
        va.z = (va.z + DT * fz * invm) * DRAG;

        xa.x += DT * va.x;
        xa.y += DT * va.y;
        xa.z += DT * va.z;
        xa.z = fmaxf(xa.z, 0.0f);
        if (xa.z == 0.0f) va.z = 0.0f;

        xvout[2 * vid]     = xa;
        xvout[2 * vid + 1] = va;
    }
}

__global__ void pack_k(const float4* __restrict__ xv, float* __restrict__ out, int nv) {
    int i = blockIdx.x * blockDim.x + threadIdx.x;
    if (i < nv) {
        float4 x = xv[2 * i];
        out[3 * i + 0] = x.x;
        out[3 * i + 1] = x.y;
        out[3 * i + 2] = x.z;
    }
}

extern "C" void kernel_launch(void* const* d_in, const int* in_sizes, int n_in,
                              void* d_out, int out_size, void* d_ws, size_t ws_size,
                              hipStream_t stream) {
    const float* x0      = (const float*)d_in[0];   // (NV,3) fp32
    const int2*  springs = (const int2*)d_in[1];    // (NS,2) int32
    const float* rest    = (const float*)d_in[2];   // (NS,)  fp32
    const float* mass    = (const float*)d_in[3];   // (NV,)  fp32

    const int ns = in_sizes[2];        // 1,000,000
    const int nv = in_sizes[3];        // 100,000
    const int nb = (nv + 255) / 256;

    // workspace layout
    char* ws = (char*)d_ws;
    size_t o = 0;
    float4* xva = (float4*)(ws + o); o += (size_t)nv * 32;   // x,v interleaved
    float4* xvb = (float4*)(ws + o); o += (size_t)nv * 32;
    int* deg    = (int*)(ws + o);    o += (((size_t)nv * 4 + 15) & ~15ull);
    int2* adj   = (int2*)(ws + o);                            // nv*64 entries (51.2 MB)

    const int STRIDE = 64;

    dim3 blk(256);
    dim3 vgrid(nb);
    dim3 sgrid((ns + 255) / 256);
    dim3 subgrid(((size_t)nv * 4 + 255) / 256);   // 4 lanes per vertex

    // one-time build (replayed every call; amortized over 100 substeps)
    init_k<<<vgrid, blk, 0, stream>>>(x0, xva, deg, nv);
    fill_stride_k<<<sgrid, blk, 0, stream>>>(springs, rest, deg, adj, ns, STRIDE);

    const int NSUB = 100;
    float4* xi = xva;
    float4* xo = xvb;
    for (int t = 0; t < NSUB; ++t) {
        substep_k<<<subgrid, blk, 0, stream>>>(xi, xo, adj, deg, mass, nv, STRIDE);
        float4* tmp = xi; xi = xo; xo = tmp;
    }
    pack_k<<<vgrid, blk, 0, stream>>>(xi, (float*)d_out, nv);
}

// Round 11
// 2099.395 us; speedup vs baseline: 1.1115x; 1.1115x over previous
//
#include <hip/hip_runtime.h>

#define DT 5e-5f
#define SPRING_Y 30000.0f
#define DASHPOT 100.0f
// exp(-DT * DRAG_DAMPING) = exp(-5e-5)
#define DRAG 0.9999500012499792f

// xv layout: xv[2*i] = position, xv[2*i+1] = velocity (w unused).
// 32B per vertex, 32B-aligned -> both halves in ONE 64B line.
// adj entry: (neighbor, 1/rest as bits); force formula is symmetric, no sign.
// Stride layout: vertex v's entries at adj[v*64 .. v*64+deg[v]).
// substep: 8 lanes/vertex; lanes pair up so one 64B xv line is fetched by
// both lanes of a pair in ONE instruction (halves TA line-touches/entry).

// ---------- one-time (per launch) build ----------

__global__ void init_k(const float* __restrict__ x0, float4* __restrict__ xv,
                       int* __restrict__ deg, int nv) {
    int i = blockIdx.x * blockDim.x + threadIdx.x;
    if (i < nv) {
        xv[2 * i]     = make_float4(x0[3 * i], x0[3 * i + 1], x0[3 * i + 2], 0.0f);
        xv[2 * i + 1] = make_float4(0.0f, 0.0f, 0.0f, 0.0f);
        deg[i] = 0;
    }
}

__global__ void fill_stride_k(const int2* __restrict__ springs,
                              const float* __restrict__ rest,
                              int* __restrict__ deg, int2* __restrict__ adj,
                              int ns, int S) {
    int s = blockIdx.x * blockDim.x + threadIdx.x;
    if (s < ns) {
        int2 p = springs[s];
        int ir = __float_as_int(1.0f / rest[s]);
        int a = atomicAdd(&deg[p.x], 1);
        adj[p.x * S + a] = make_int2(p.y, ir);
        int b = atomicAdd(&deg[p.y], 1);
        adj[p.y * S + b] = make_int2(p.x, ir);
    }
}

// ---------- fused per-substep kernel ----------

__global__ void __launch_bounds__(256) substep_k(
        const float4* __restrict__ xvin, float4* __restrict__ xvout,
        const int2* __restrict__ adj, const int* __restrict__ deg,
        const float* __restrict__ mass, int nv, int S) {
    int gid = blockIdx.x * blockDim.x + threadIdx.x;
    int vid = gid >> 3;
    int sub = gid & 7;
    if (vid >= nv) return;

    float4 xa = xvin[2 * vid];
    float4 va = xvin[2 * vid + 1];
    int s0 = vid * S;
    int s1 = s0 + deg[vid];
    int last = s1 - 1;                 // segment-clamp target (valid when deg>0)
    int par = sub & 1;                 // lane parity within its pair

    float fx = 0.0f, fy = 0.0f, fz = 0.0f;
    int pf = s0 + (sub & ~1);          // pair's first entry index
    int j  = pf + par;                 // this lane's own entry index

    if (pf < s1) {                     // pair-uniform: both pair lanes iterate together
        int2 e = adj[min(j, last)];    // own entry (clamped dup if tail-invalid)
        for (;;) {
            int2 en = adj[min(j + 8, last)];   // depth-1 prefetch, segment-clamped

            float msk = (j <= last) ? 1.0f : 0.0f;
            int n = e.x;
            int pn = __shfl_xor(n, 1);          // partner's neighbor
            int nA = par ? pn : n;              // even lane's entry
            int nB = par ? n : pn;              // odd lane's entry

            // instr1: pair fetches A's 64B line (two 16B halves, one line-touch)
            float4 t1 = xvin[2 * nA + par];         // even: xA, odd: vA
            // instr2: pair fetches B's line
            float4 t2 = xvin[2 * nB + (1 - par)];   // even: vB, odd: xB

            // reassemble own entry's (x,v)
            float4 xb, u;
            xb.x = par ? t2.x : t1.x;
            xb.y = par ? t2.y : t1.y;
            xb.z = par ? t2.z : t1.z;
            u.x  = par ? t1.x : t2.x;   // the half this lane must SEND
            u.y  = par ? t1.y : t2.y;
            u.z  = par ? t1.z : t2.z;
            float4 vb;
            vb.x = __shfl_xor(u.x, 1);
            vb.y = __shfl_xor(u.y, 1);
            vb.z = __shfl_xor(u.z, 1);

            float invr = __int_as_float(e.y);
            float dx = xb.x - xa.x, dy = xb.y - xa.y, dz = xb.z - xa.z;
            float len = sqrtf(dx * dx + dy * dy + dz * dz);
            float il = 1.0f / len;              // clamped dups are valid: len > 0
            float ddx = dx * il, ddy = dy * il, ddz = dz * il;
            float vrel = (vb.x - va.x) * ddx + (vb.y - va.y) * ddy + (vb.z - va.z) * ddz;
            float coef = (SPRING_Y * (len * invr - 1.0f) + DASHPOT * vrel) * msk;
            fx += coef * ddx;
            fy += coef * ddy;
            fz += coef * ddz;

            pf += 8;
            if (pf >= s1) break;
            j += 8;
            e = en;
        }
    }

    // reduce across the 8 lanes of this vertex (xor stays within the group)
    fx += __shfl_xor(fx, 1);
    fx += __shfl_xor(fx, 2);
    fx += __shfl_xor(fx, 4);
    fy += __shfl_xor(fy, 1);
    fy += __shfl_xor(fy, 2);
    fy += __shfl_xor(fy, 4);
    fz += __shfl_xor(fz, 1);
    fz += __shfl_xor(fz, 2);
    fz += __shfl_xor(fz, 4);

    if (sub == 0) {
        float m = mass[vid];
        fz += m * (-9.8f);
        float invm = 1.0f / m;

        va.x = (va.x + DT * fx * invm) * DRAG;
        va.y = (va.y + DT * fy * invm) * DRAG;
        va.z = (va.z + DT * fz * invm) * DRAG;

        xa.x += DT * va.x;
        xa.y += DT * va.y;
        xa.z += DT * va.z;
        xa.z = fmaxf(xa.z, 0.0f);
        if (xa.z == 0.0f) va.z = 0.0f;

        xvout[2 * vid]     = xa;
        xvout[2 * vid + 1] = va;
    }
}

__global__ void pack_k(const float4* __restrict__ xv, float* __restrict__ out, int nv) {
    int i = blockIdx.x * blockDim.x + threadIdx.x;
    if (i < nv) {
        float4 x = xv[2 * i];
        out[3 * i + 0] = x.x;
        out[3 * i + 1] = x.y;
        out[3 * i + 2] = x.z;
    }
}

extern "C" void kernel_launch(void* const* d_in, const int* in_sizes, int n_in,
                              void* d_out, int out_size, void* d_ws, size_t ws_size,
                              hipStream_t stream) {
    const float* x0      = (const float*)d_in[0];   // (NV,3) fp32
    const int2*  springs = (const int2*)d_in[1];    // (NS,2) int32
    const float* rest    = (const float*)d_in[2];   // (NS,)  fp32
    const float* mass    = (const float*)d_in[3];   // (NV,)  fp32

    const int ns = in_sizes[2];        // 1,000,000
    const int nv = in_sizes[3];        // 100,000
    const int nb = (nv + 255) / 256;

    // workspace layout
    char* ws = (char*)d_ws;
    size_t o = 0;
    float4* xva = (float4*)(ws + o); o += (size_t)nv * 32;   // x,v interleaved
    float4* xvb = (float4*)(ws + o); o += (size_t)nv * 32;
    int* deg    = (int*)(ws + o);    o += (((size_t)nv * 4 + 15) & ~15ull);
    int2* adj   = (int2*)(ws + o);                            // nv*64 entries (51.2 MB)

    const int STRIDE = 64;

    dim3 blk(256);
    dim3 vgrid(nb);
    dim3 sgrid((ns + 255) / 256);
    dim3 subgrid(((size_t)nv * 8 + 255) / 256);   // 8 lanes per vertex

    // one-time build (replayed every call; amortized over 100 substeps)
    init_k<<<vgrid, blk, 0, stream>>>(x0, xva, deg, nv);
    fill_stride_k<<<sgrid, blk, 0, stream>>>(springs, rest, deg, adj, ns, STRIDE);

    const int NSUB = 100;
    float4* xi = xva;
    float4* xo = xvb;
    for (int t = 0; t < NSUB; ++t) {
        substep_k<<<subgrid, blk, 0, stream>>>(xi, xo, adj, deg, mass, nv, STRIDE);
        float4* tmp = xi; xi = xo; xo = tmp;
    }
    pack_k<<<vgrid, blk, 0, stream>>>(xi, (float*)d_out, nv);
}

// Round 12
// 2091.382 us; speedup vs baseline: 1.1158x; 1.0038x over previous
//
#include <hip/hip_runtime.h>

#define DT 5e-5f
#define SPRING_Y 30000.0f
#define DASHPOT 100.0f
// exp(-DT * DRAG_DAMPING) = exp(-5e-5)
#define DRAG 0.9999500012499792f

// xv layout: xv[2*i] = position, xv[2*i+1] = velocity (w unused).
// 32B per vertex, 32B-aligned -> both halves in ONE 64B line.
// adj entry: (neighbor, 1/rest as bits); force formula is symmetric, no sign.
// Stride layout: vertex v's entries at adj[v*64 .. v*64+deg[v]); segment base
// is 512B-aligned, so 2-entry (int4) loads are 16B-aligned.
// substep: 8 lanes/vertex, 2 entries per lane per iteration via ONE int4 adj
// load -> 2.5 VMEM lane-ops per entry (adj 0.5 + gathers 2), no prefetch.

// ---------- one-time (per launch) build ----------

__global__ void init_k(const float* __restrict__ x0, float4* __restrict__ xv,
                       int* __restrict__ deg, int nv) {
    int i = blockIdx.x * blockDim.x + threadIdx.x;
    if (i < nv) {
        xv[2 * i]     = make_float4(x0[3 * i], x0[3 * i + 1], x0[3 * i + 2], 0.0f);
        xv[2 * i + 1] = make_float4(0.0f, 0.0f, 0.0f, 0.0f);
        deg[i] = 0;
    }
}

__global__ void fill_stride_k(const int2* __restrict__ springs,
                              const float* __restrict__ rest,
                              int* __restrict__ deg, int2* __restrict__ adj,
                              int ns, int S) {
    int s = blockIdx.x * blockDim.x + threadIdx.x;
    if (s < ns) {
        int2 p = springs[s];
        int ir = __float_as_int(1.0f / rest[s]);
        int a = atomicAdd(&deg[p.x], 1);
        adj[p.x * S + a] = make_int2(p.y, ir);
        int b = atomicAdd(&deg[p.y], 1);
        adj[p.y * S + b] = make_int2(p.x, ir);
    }
}

// ---------- fused per-substep kernel ----------

__device__ __forceinline__ void accum_pair(const float4& xa, const float4& va,
                                           const float4& xb, const float4& vb,
                                           float invr, float msk,
                                           float& fx, float& fy, float& fz) {
    float dx = xb.x - xa.x, dy = xb.y - xa.y, dz = xb.z - xa.z;
    float len = sqrtf(dx * dx + dy * dy + dz * dz);
    float il = 1.0f / len;                  // sanitized dup entries: len > 0
    float ddx = dx * il, ddy = dy * il, ddz = dz * il;
    float vrel = (vb.x - va.x) * ddx + (vb.y - va.y) * ddy + (vb.z - va.z) * ddz;
    float coef = (SPRING_Y * (len * invr - 1.0f) + DASHPOT * vrel) * msk;
    fx += coef * ddx;
    fy += coef * ddy;
    fz += coef * ddz;
}

__global__ void __launch_bounds__(256) substep_k(
        const float4* __restrict__ xvin, float4* __restrict__ xvout,
        const int4* __restrict__ adjq, const int* __restrict__ deg,
        const float* __restrict__ mass, int nv, int S) {
    int gid = blockIdx.x * blockDim.x + threadIdx.x;
    int vid = gid >> 3;
    int sub = gid & 7;
    if (vid >= nv) return;

    float4 xa = xvin[2 * vid];
    float4 va = xvin[2 * vid + 1];
    int d = deg[vid];
    int q0 = vid * (S >> 1);           // pair-granular segment base (int4 index)
    int qe = q0 + ((d + 1) >> 1);      // exclusive end over valid pairs

    float fx = 0.0f, fy = 0.0f, fz = 0.0f;
    for (int q = q0 + sub; q < qe; q += 8) {
        int4 raw = adjq[q];            // entries 2(q-q0), 2(q-q0)+1 of this vertex
        int rel1 = ((q - q0) << 1) + 1;
        bool m1 = rel1 < d;            // second entry valid?
        int n0 = raw.x;
        int n1 = m1 ? raw.z : raw.x;   // sanitize poison slot -> valid dup
        float ir1 = m1 ? __int_as_float(raw.w) : 0.0f;

        // issue all gathers before any use
        float4 xb0 = xvin[2 * n0];
        float4 vb0 = xvin[2 * n0 + 1];
        float4 xb1 = xvin[2 * n1];
        float4 vb1 = xvin[2 * n1 + 1];

        accum_pair(xa, va, xb0, vb0, __int_as_float(raw.y), 1.0f, fx, fy, fz);
        accum_pair(xa, va, xb1, vb1, ir1, m1 ? 1.0f : 0.0f, fx, fy, fz);
    }

    // reduce across the 8 lanes of this vertex (xor stays within the group)
    fx += __shfl_xor(fx, 1);
    fx += __shfl_xor(fx, 2);
    fx += __shfl_xor(fx, 4);
    fy += __shfl_xor(fy, 1);
    fy += __shfl_xor(fy, 2);
    fy += __shfl_xor(fy, 4);
    fz += __shfl_xor(fz, 1);
    fz += __shfl_xor(fz, 2);
    fz += __shfl_xor(fz, 4);

    if (sub == 0) {
        float m = mass[vid];
        fz += m * (-9.8f);
        float invm = 1.0f / m;

        va.x = (va.x + DT * fx * invm) * DRAG;
        va.y = (va.y + DT * fy * invm) * DRAG;
        va.z = (va.z + DT * fz * invm) * DRAG;

        xa.x += DT * va.x;
        xa.y += DT * va.y;
        xa.z += DT * va.z;
        xa.z = fmaxf(xa.z, 0.0f);
        if (xa.z == 0.0f) va.z = 0.0f;

        xvout[2 * vid]     = xa;
        xvout[2 * vid + 1] = va;
    }
}

__global__ void pack_k(const float4* __restrict__ xv, float* __restrict__ out, int nv) {
    int i = blockIdx.x * blockDim.x + threadIdx.x;
    if (i < nv) {
        float4 x = xv[2 * i];
        out[3 * i + 0] = x.x;
        out[3 * i + 1] = x.y;
        out[3 * i + 2] = x.z;
    }
}

extern "C" void kernel_launch(void* const* d_in, const int* in_sizes, int n_in,
                              void* d_out, int out_size, void* d_ws, size_t ws_size,
                              hipStream_t stream) {
    const float* x0      = (const float*)d_in[0];   // (NV,3) fp32
    const int2*  springs = (const int2*)d_in[1];    // (NS,2) int32
    const float* rest    = (const float*)d_in[2];   // (NS,)  fp32
    const float* mass    = (const float*)d_in[3];   // (NV,)  fp32

    const int ns = in_sizes[2];        // 1,000,000
    const int nv = in_sizes[3];        // 100,000
    const int nb = (nv + 255) / 256;

    // workspace layout
    char* ws = (char*)d_ws;
    size_t o = 0;
    float4* xva = (float4*)(ws + o); o += (size_t)nv * 32;   // x,v interleaved
    float4* xvb = (float4*)(ws + o); o += (size_t)nv * 32;
    int* deg    = (int*)(ws + o);    o += (((size_t)nv * 4 + 15) & ~15ull);
    int2* adj   = (int2*)(ws + o);                            // nv*64 entries (51.2 MB)

    const int STRIDE = 64;

    dim3 blk(256);
    dim3 vgrid(nb);
    dim3 sgrid((ns + 255) / 256);
    dim3 subgrid(((size_t)nv * 8 + 255) / 256);   // 8 lanes per vertex

    // one-time build (replayed every call; amortized over 100 substeps)
    init_k<<<vgrid, blk, 0, stream>>>(x0, xva, deg, nv);
    fill_stride_k<<<sgrid, blk, 0, stream>>>(springs, rest, deg, adj, ns, STRIDE);

    const int NSUB = 100;
    float4* xi = xva;
    float4* xo = xvb;
    for (int t = 0; t < NSUB; ++t) {
        substep_k<<<subgrid, blk, 0, stream>>>(xi, xo, (const int4*)adj, deg, mass, nv, STRIDE);
        float4* tmp = xi; xi = xo; xo = tmp;
    }
    pack_k<<<vgrid, blk, 0, stream>>>(xi, (float*)d_out, nv);
}

// Round 13
// 2032.419 us; speedup vs baseline: 1.1481x; 1.0290x over previous
//
#include <hip/hip_runtime.h>
#include <hip/hip_fp16.h>

#define DT 5e-5f
#define SPRING_Y 30000.0f
#define DASHPOT 100.0f
// exp(-DT * DRAG_DAMPING) = exp(-5e-5)
#define DRAG 0.9999500012499792f

// xv layout: xv[2*i] = position, xv[2*i+1] = velocity (w unused).
// 32B per vertex, 32B-aligned -> both halves in ONE 64B line.
// adj entry: 4 BYTES: (neighbor_idx:17) << 15 | (fp16(1/rest) & 0x7fff).
//   idx < 2^17 = 131072 >= nv; 1/rest > 0 so fp16 sign bit is free; values
//   are fp16-normal range so decode is (h<<13) + (112<<23).
// Stride layout: vertex v's entries at adj[v*64 .. v*64+deg[v]) -- 256B-aligned
// segments, built by one atomicAdd pass, no count/scan kernels.
// substep: 8 lanes/vertex; lane pairs fetch each 64B xv line cooperatively
// (R10-proven: one line-touch per entry).

// ---------- one-time (per launch) build ----------

__global__ void init_k(const float* __restrict__ x0, float4* __restrict__ xv,
                       int* __restrict__ deg, int nv) {
    int i = blockIdx.x * blockDim.x + threadIdx.x;
    if (i < nv) {
        xv[2 * i]     = make_float4(x0[3 * i], x0[3 * i + 1], x0[3 * i + 2], 0.0f);
        xv[2 * i + 1] = make_float4(0.0f, 0.0f, 0.0f, 0.0f);
        deg[i] = 0;
    }
}

__global__ void fill_stride_k(const int2* __restrict__ springs,
                              const float* __restrict__ rest,
                              int* __restrict__ deg, unsigned* __restrict__ adj,
                              int ns, int S) {
    int s = blockIdx.x * blockDim.x + threadIdx.x;
    if (s < ns) {
        int2 p = springs[s];
        unsigned h = __half_as_ushort(__float2half(1.0f / rest[s])) & 0x7fffu;
        int a = atomicAdd(&deg[p.x], 1);
        adj[p.x * S + a] = ((unsigned)p.y << 15) | h;
        int b = atomicAdd(&deg[p.y], 1);
        adj[p.y * S + b] = ((unsigned)p.x << 15) | h;
    }
}

// ---------- fused per-substep kernel ----------

__global__ void __launch_bounds__(256) substep_k(
        const float4* __restrict__ xvin, float4* __restrict__ xvout,
        const unsigned* __restrict__ adj, const int* __restrict__ deg,
        const float* __restrict__ mass, int nv, int S) {
    int gid = blockIdx.x * blockDim.x + threadIdx.x;
    int vid = gid >> 3;
    int sub = gid & 7;
    if (vid >= nv) return;

    float4 xa = xvin[2 * vid];
    float4 va = xvin[2 * vid + 1];
    int s0 = vid * S;
    int s1 = s0 + deg[vid];
    int last = s1 - 1;                 // segment-clamp target (valid when deg>0)
    int par = sub & 1;                 // lane parity within its pair

    float fx = 0.0f, fy = 0.0f, fz = 0.0f;
    int pf = s0 + (sub & ~1);          // pair's first entry index
    int j  = pf + par;                 // this lane's own entry index

    if (pf < s1) {                     // pair-uniform: both pair lanes iterate together
        for (;;) {
            unsigned e = adj[min(j, last)];     // own entry (clamped dup if tail)
            float msk = (j <= last) ? 1.0f : 0.0f;
            int n = (int)(e >> 15);
            float invr = __uint_as_float(((e & 0x7fffu) << 13) + (112u << 23));

            int pn = __shfl_xor(n, 1);          // partner's neighbor
            int nA = par ? pn : n;              // even lane's entry
            int nB = par ? n : pn;              // odd lane's entry

            // instr1: pair fetches A's 64B line (two 16B halves, one line-touch)
            float4 t1 = xvin[2 * nA + par];         // even: xA, odd: vA
            // instr2: pair fetches B's line
            float4 t2 = xvin[2 * nB + (1 - par)];   // even: vB, odd: xB

            // reassemble own entry's (x,v)
            float4 xb, u;
            xb.x = par ? t2.x : t1.x;
            xb.y = par ? t2.y : t1.y;
            xb.z = par ? t2.z : t1.z;
            u.x  = par ? t1.x : t2.x;   // the half this lane must SEND
            u.y  = par ? t1.y : t2.y;
            u.z  = par ? t1.z : t2.z;
            float4 vb;
            vb.x = __shfl_xor(u.x, 1);
            vb.y = __shfl_xor(u.y, 1);
            vb.z = __shfl_xor(u.z, 1);

            float dx = xb.x - xa.x, dy = xb.y - xa.y, dz = xb.z - xa.z;
            float len = sqrtf(dx * dx + dy * dy + dz * dz);
            float il = 1.0f / len;              // clamped dups are valid: len > 0
            float ddx = dx * il, ddy = dy * il, ddz = dz * il;
            float vrel = (vb.x - va.x) * ddx + (vb.y - va.y) * ddy + (vb.z - va.z) * ddz;
            float coef = (SPRING_Y * (len * invr - 1.0f) + DASHPOT * vrel) * msk;
            fx += coef * ddx;
            fy += coef * ddy;
            fz += coef * ddz;

            pf += 8;
            if (pf >= s1) break;
            j += 8;
        }
    }

    // reduce across the 8 lanes of this vertex (xor stays within the group)
    fx += __shfl_xor(fx, 1);
    fx += __shfl_xor(fx, 2);
    fx += __shfl_xor(fx, 4);
    fy += __shfl_xor(fy, 1);
    fy += __shfl_xor(fy, 2);
    fy += __shfl_xor(fy, 4);
    fz += __shfl_xor(fz, 1);
    fz += __shfl_xor(fz, 2);
    fz += __shfl_xor(fz, 4);

    if (sub == 0) {
        float m = mass[vid];
        fz += m * (-9.8f);
        float invm = 1.0f / m;

        va.x = (va.x + DT * fx * invm) * DRAG;
        va.y = (va.y + DT * fy * invm) * DRAG;
        va.z = (va.z + DT * fz * invm) * DRAG;

        xa.x += DT * va.x;
        xa.y += DT * va.y;
        xa.z += DT * va.z;
        xa.z = fmaxf(xa.z, 0.0f);
        if (xa.z == 0.0f) va.z = 0.0f;

        xvout[2 * vid]     = xa;
        xvout[2 * vid + 1] = va;
    }
}

__global__ void pack_k(const float4* __restrict__ xv, float* __restrict__ out, int nv) {
    int i = blockIdx.x * blockDim.x + threadIdx.x;
    if (i < nv) {
        float4 x = xv[2 * i];
        out[3 * i + 0] = x.x;
        out[3 * i + 1] = x.y;
        out[3 * i + 2] = x.z;
    }
}

extern "C" void kernel_launch(void* const* d_in, const int* in_sizes, int n_in,
                              void* d_out, int out_size, void* d_ws, size_t ws_size,
                              hipStream_t stream) {
    const float* x0      = (const float*)d_in[0];   // (NV,3) fp32
    const int2*  springs = (const int2*)d_in[1];    // (NS,2) int32
    const float* rest    = (const float*)d_in[2];   // (NS,)  fp32
    const float* mass    = (const float*)d_in[3];   // (NV,)  fp32

    const int ns = in_sizes[2];        // 1,000,000
    const int nv = in_sizes[3];        // 100,000
    const int nb = (nv + 255) / 256;

    // workspace layout
    char* ws = (char*)d_ws;
    size_t o = 0;
    float4* xva   = (float4*)(ws + o); o += (size_t)nv * 32;   // x,v interleaved
    float4* xvb   = (float4*)(ws + o); o += (size_t)nv * 32;
    int* deg      = (int*)(ws + o);    o += (((size_t)nv * 4 + 15) & ~15ull);
    unsigned* adj = (unsigned*)(ws + o);                        // nv*64*4B = 25.6 MB

    const int STRIDE = 64;

    dim3 blk(256);
    dim3 vgrid(nb);
    dim3 sgrid((ns + 255) / 256);
    dim3 subgrid(((size_t)nv * 8 + 255) / 256);   // 8 lanes per vertex

    // one-time build (replayed every call; amortized over 100 substeps)
    init_k<<<vgrid, blk, 0, stream>>>(x0, xva, deg, nv);
    fill_stride_k<<<sgrid, blk, 0, stream>>>(springs, rest, deg, adj, ns, STRIDE);

    const int NSUB = 100;
    float4* xi = xva;
    float4* xo = xvb;
    for (int t = 0; t < NSUB; ++t) {
        substep_k<<<subgrid, blk, 0, stream>>>(xi, xo, adj, deg, mass, nv, STRIDE);
        float4* tmp = xi; xi = xo; xo = tmp;
    }
    pack_k<<<vgrid, blk, 0, stream>>>(xi, (float*)d_out, nv);
}

// Round 14
// 1946.994 us; speedup vs baseline: 1.1985x; 1.0439x over previous
//
#include <hip/hip_runtime.h>
#include <hip/hip_fp16.h>

#define DT 5e-5f
#define SPRING_Y 30000.0f
#define DASHPOT 100.0f
// exp(-DT * DRAG_DAMPING) = exp(-5e-5)
#define DRAG 0.9999500012499792f

// xv layout: xv[2*i] = position, xv[2*i+1] = velocity (w unused).
// 32B per vertex, 32B-aligned -> both halves in ONE 64B line.
// adj entry: 4 BYTES: (neighbor_idx:17) << 15 | (fp16(1/rest) & 0x7fff).
// Stride layout: vertex v's entries at adj[v*64 .. v*64+deg[v]).
// Fill is SLICE-OWNED: 8 vertex slices (~3.2MB of adj each, one XCD-L2 worth);
// block b handles spring chunk b>>3 and writes only endpoints in slice b&7
// (round-robin dispatch pins slice<->XCD, so writes coalesce in that L2).
// substep: 8 lanes/vertex; lane pairs fetch each 64B xv line cooperatively
// (R10-proven). Last substep also writes the packed (NV,3) output directly.

// ---------- one-time (per launch) build ----------

__global__ void init_k(const float* __restrict__ x0, float4* __restrict__ xv,
                       int* __restrict__ deg, int nv) {
    int i = blockIdx.x * blockDim.x + threadIdx.x;
    if (i < nv) {
        xv[2 * i]     = make_float4(x0[3 * i], x0[3 * i + 1], x0[3 * i + 2], 0.0f);
        xv[2 * i + 1] = make_float4(0.0f, 0.0f, 0.0f, 0.0f);
        deg[i] = 0;
    }
}

__global__ void fill_sliced_k(const int2* __restrict__ springs,
                              const float* __restrict__ rest,
                              int* __restrict__ deg, unsigned* __restrict__ adj,
                              int ns, int nv, int S) {
    int b = blockIdx.x;
    int slice = b & 7;
    int s = (b >> 3) * blockDim.x + threadIdx.x;
    if (s >= ns) return;

    int lo = (int)(((long long)slice * nv) >> 3);
    int hi = (int)(((long long)(slice + 1) * nv) >> 3);

    int2 p = springs[s];
    unsigned h = __half_as_ushort(__float2half(1.0f / rest[s])) & 0x7fffu;
    if (p.x >= lo && p.x < hi) {
        int a = atomicAdd(&deg[p.x], 1);
        adj[p.x * S + a] = ((unsigned)p.y << 15) | h;
    }
    if (p.y >= lo && p.y < hi) {
        int c = atomicAdd(&deg[p.y], 1);
        adj[p.y * S + c] = ((unsigned)p.x << 15) | h;
    }
}

// ---------- fused per-substep kernel ----------

__global__ void __launch_bounds__(256) substep_k(
        const float4* __restrict__ xvin, float4* __restrict__ xvout,
        const unsigned* __restrict__ adj, const int* __restrict__ deg,
        const float* __restrict__ mass, int nv, int S,
        float* __restrict__ out) {
    int gid = blockIdx.x * blockDim.x + threadIdx.x;
    int vid = gid >> 3;
    int sub = gid & 7;
    if (vid >= nv) return;

    float4 xa = xvin[2 * vid];
    float4 va = xvin[2 * vid + 1];
    int s0 = vid * S;
    int s1 = s0 + deg[vid];
    int last = s1 - 1;                 // segment-clamp target (valid when deg>0)
    int par = sub & 1;                 // lane parity within its pair

    float fx = 0.0f, fy = 0.0f, fz = 0.0f;
    int pf = s0 + (sub & ~1);          // pair's first entry index
    int j  = pf + par;                 // this lane's own entry index

    if (pf < s1) {                     // pair-uniform: both pair lanes iterate together
        for (;;) {
            unsigned e = adj[min(j, last)];     // own entry (clamped dup if tail)
            float msk = (j <= last) ? 1.0f : 0.0f;
            int n = (int)(e >> 15);
            float invr = __uint_as_float(((e & 0x7fffu) << 13) + (112u << 23));

            int pn = __shfl_xor(n, 1);          // partner's neighbor
            int nA = par ? pn : n;              // even lane's entry
            int nB = par ? n : pn;              // odd lane's entry

            // instr1: pair fetches A's 64B line (two 16B halves, one line-touch)
            float4 t1 = xvin[2 * nA + par];         // even: xA, odd: vA
            // instr2: pair fetches B's line
            float4 t2 = xvin[2 * nB + (1 - par)];   // even: vB, odd: xB

            // reassemble own entry's (x,v)
            float4 xb, u;
            xb.x = par ? t2.x : t1.x;
            xb.y = par ? t2.y : t1.y;
            xb.z = par ? t2.z : t1.z;
            u.x  = par ? t1.x : t2.x;   // the half this lane must SEND
            u.y  = par ? t1.y : t2.y;
            u.z  = par ? t1.z : t2.z;
            float4 vb;
            vb.x = __shfl_xor(u.x, 1);
            vb.y = __shfl_xor(u.y, 1);
            vb.z = __shfl_xor(u.z, 1);

            float dx = xb.x - xa.x, dy = xb.y - xa.y, dz = xb.z - xa.z;
            float len = sqrtf(dx * dx + dy * dy + dz * dz);
            float il = 1.0f / len;              // clamped dups are valid: len > 0
            float ddx = dx * il, ddy = dy * il, ddz = dz * il;
            float vrel = (vb.x - va.x) * ddx + (vb.y - va.y) * ddy + (vb.z - va.z) * ddz;
            float coef = (SPRING_Y * (len * invr - 1.0f) + DASHPOT * vrel) * msk;
            fx += coef * ddx;
            fy += coef * ddy;
            fz += coef * ddz;

            pf += 8;
            if (pf >= s1) break;
            j += 8;
        }
    }

    // reduce across the 8 lanes of this vertex (xor stays within the group)
    fx += __shfl_xor(fx, 1);
    fx += __shfl_xor(fx, 2);
    fx += __shfl_xor(fx, 4);
    fy += __shfl_xor(fy, 1);
    fy += __shfl_xor(fy, 2);
    fy += __shfl_xor(fy, 4);
    fz += __shfl_xor(fz, 1);
    fz += __shfl_xor(fz, 2);
    fz += __shfl_xor(fz, 4);

    if (sub == 0) {
        float m = mass[vid];
        fz += m * (-9.8f);
        float invm = 1.0f / m;

        va.x = (va.x + DT * fx * invm) * DRAG;
        va.y = (va.y + DT * fy * invm) * DRAG;
        va.z = (va.z + DT * fz * invm) * DRAG;

        xa.x += DT * va.x;
        xa.y += DT * va.y;
        xa.z += DT * va.z;
        xa.z = fmaxf(xa.z, 0.0f);
        if (xa.z == 0.0f) va.z = 0.0f;

        xvout[2 * vid]     = xa;
        xvout[2 * vid + 1] = va;

        if (out) {                     // final substep: emit packed (NV,3) output
            out[3 * vid + 0] = xa.x;
            out[3 * vid + 1] = xa.y;
            out[3 * vid + 2] = xa.z;
        }
    }
}

extern "C" void kernel_launch(void* const* d_in, const int* in_sizes, int n_in,
                              void* d_out, int out_size, void* d_ws, size_t ws_size,
                              hipStream_t stream) {
    const float* x0      = (const float*)d_in[0];   // (NV,3) fp32
    const int2*  springs = (const int2*)d_in[1];    // (NS,2) int32
    const float* rest    = (const float*)d_in[2];   // (NS,)  fp32
    const float* mass    = (const float*)d_in[3];   // (NV,)  fp32

    const int ns = in_sizes[2];        // 1,000,000
    const int nv = in_sizes[3];        // 100,000
    const int nb = (nv + 255) / 256;

    // workspace layout
    char* ws = (char*)d_ws;
    size_t o = 0;
    float4* xva   = (float4*)(ws + o); o += (size_t)nv * 32;   // x,v interleaved
    float4* xvb   = (float4*)(ws + o); o += (size_t)nv * 32;
    int* deg      = (int*)(ws + o);    o += (((size_t)nv * 4 + 15) & ~15ull);
    unsigned* adj = (unsigned*)(ws + o);                        // nv*64*4B = 25.6 MB

    const int STRIDE = 64;

    dim3 blk(256);
    dim3 vgrid(nb);
    dim3 fgrid(8 * ((ns + 255) / 256));           // 8 slices x spring chunks
    dim3 subgrid(((size_t)nv * 8 + 255) / 256);   // 8 lanes per vertex

    // one-time build (replayed every call; amortized over 100 substeps)
    init_k<<<vgrid, blk, 0, stream>>>(x0, xva, deg, nv);
    fill_sliced_k<<<fgrid, blk, 0, stream>>>(springs, rest, deg, adj, ns, nv, STRIDE);

    const int NSUB = 100;
    float4* xi = xva;
    float4* xo = xvb;
    for (int t = 0; t < NSUB; ++t) {
        float* out = (t == NSUB - 1) ? (float*)d_out : nullptr;
        substep_k<<<subgrid, blk, 0, stream>>>(xi, xo, adj, deg, mass, nv, STRIDE, out);
        float4* tmp = xi; xi = xo; xo = tmp;
    }
}